// Round 6
// baseline (64610.175 us; speedup 1.0000x reference)
//
#include <hip/hip_runtime.h>

// Problem constants (from reference)
#define SEQ   8192
#define HID   256
#define G3    768      // 3*HID
#define TSTART 1024    // SEQ/8
#define NEGD  1365     // SEQ/6
#define TCNT  5791     // (SEQ - 10 - NEGD - 4 + 2) - TSTART
#define DENOMF 23164.0f // TCNT*4

typedef _Float16 half2_t __attribute__((ext_vector_type(2)));
typedef _Float16 half8_t __attribute__((ext_vector_type(8)));
typedef float    f32x4  __attribute__((ext_vector_type(4)));

__device__ __forceinline__ float fdot2(half2_t a, half2_t b, float c) {
#if __has_builtin(__builtin_amdgcn_fdot2)
  return __builtin_amdgcn_fdot2(a, b, c, false);
#else
  return c + (float)a.x * (float)b.x + (float)a.y * (float)b.y;
#endif
}

__device__ __forceinline__ half2_t h2_from_u32(unsigned int u) {
  return __builtin_bit_cast(half2_t, u);
}

__device__ __forceinline__ float sigmoidf_fast(float x) {
  return 1.0f / (1.0f + __expf(-x));
}
// tanh via sigmoid form: safe at both extremes (exp under/overflow -> +-1)
__device__ __forceinline__ float tanhf_fast(float x) {
  return 2.0f / (1.0f + __expf(-2.0f * x)) - 1.0f;
}

// Sum across the 4 lanes of each aligned quad (lane^1 then lane^2), on the
// VALU via quad_perm DPP (0xB1=[1,0,3,2], 0x4E=[2,3,0,1]). All lanes active.
// Harness-proven in round 5 (passed correctness).
__device__ __forceinline__ float quad_sum(float x) {
#if __has_builtin(__builtin_amdgcn_update_dpp)
  int xi = __builtin_bit_cast(int, x);
  int a  = __builtin_amdgcn_update_dpp(xi, xi, 0xB1, 0xF, 0xF, false);
  float y = x + __builtin_bit_cast(float, a);
  int yi = __builtin_bit_cast(int, y);
  int b  = __builtin_amdgcn_update_dpp(yi, yi, 0x4E, 0xF, 0xF, false);
  return y + __builtin_bit_cast(float, b);
#else
  float y = x + __shfl_xor(x, 1, 64);
  return y + __shfl_xor(y, 2, 64);
#endif
}

// ---------------------------------------------------------------------------
// init: zero the loss accumulators (ws is poisoned 0xAA every call)
// ---------------------------------------------------------------------------
__global__ void init_kernel(float* accum) {
  if (threadIdx.x < 2) accum[threadIdx.x] = 0.0f;
}

// ---------------------------------------------------------------------------
// Phase A: xW = data @ Wih^T + bih -> f32 [SEQ][768]. All f32.
// grid (256, 3), block 256. Thread owns output col o; 32-row x-tile in LDS.
// ---------------------------------------------------------------------------
__global__ __launch_bounds__(256) void xw_kernel(
    const float* __restrict__ data, const float* __restrict__ Wih,
    const float* __restrict__ bih, float* __restrict__ xw)
{
  __shared__ float4 xs4[32 * 64];   // 32 rows x 256 f32 = 32 KB
  const int o  = blockIdx.y * 256 + threadIdx.x;
  const int m0 = blockIdx.x * 32;

  float* xsf = (float*)xs4;
  for (int r = 0; r < 32; ++r)
    xsf[r * 256 + threadIdx.x] = data[(size_t)(m0 + r) * 256 + threadIdx.x];
  __syncthreads();

  const float b = bih[o];
  float acc[32];
#pragma unroll
  for (int r = 0; r < 32; ++r) acc[r] = b;

  const float4* wrow = (const float4*)(Wih + (size_t)o * 256);
  for (int kc = 0; kc < 4; ++kc) {
    float4 w[16];
#pragma unroll
    for (int j = 0; j < 16; ++j) w[j] = wrow[kc * 16 + j];
#pragma unroll
    for (int r = 0; r < 32; ++r) {
      const float4* xr = xs4 + r * 64 + kc * 16;
      float a0 = 0.f, a1 = 0.f, a2 = 0.f, a3 = 0.f;
#pragma unroll
      for (int j = 0; j < 4; ++j) {
        float4 x0 = xr[4 * j + 0], x1 = xr[4 * j + 1];
        float4 x2 = xr[4 * j + 2], x3 = xr[4 * j + 3];
        float4 w0 = w[4 * j + 0], w1 = w[4 * j + 1];
        float4 w2 = w[4 * j + 2], w3 = w[4 * j + 3];
        a0 = fmaf(w0.x, x0.x, fmaf(w0.y, x0.y, fmaf(w0.z, x0.z, fmaf(w0.w, x0.w, a0))));
        a1 = fmaf(w1.x, x1.x, fmaf(w1.y, x1.y, fmaf(w1.z, x1.z, fmaf(w1.w, x1.w, a1))));
        a2 = fmaf(w2.x, x2.x, fmaf(w2.y, x2.y, fmaf(w2.z, x2.z, fmaf(w2.w, x2.w, a2))));
        a3 = fmaf(w3.x, x3.x, fmaf(w3.y, x3.y, fmaf(w3.z, x3.z, fmaf(w3.w, x3.w, a3))));
      }
      acc[r] += (a0 + a1) + (a2 + a3);
    }
  }
  for (int r = 0; r < 32; ++r)
    xw[(size_t)(m0 + r) * G3 + o] = acc[r];
}

// ---------------------------------------------------------------------------
// data row norms: one wave per row (f32 data)
// ---------------------------------------------------------------------------
__global__ __launch_bounds__(256) void rnorm_kernel(
    const float* __restrict__ data, float* __restrict__ rn)
{
  int wave = threadIdx.x >> 6, lane = threadIdx.x & 63;
  int row = blockIdx.x * 4 + wave;
  const float* xr = data + (size_t)row * HID;
  float a = xr[lane], b = xr[lane + 64], c = xr[lane + 128], d = xr[lane + 192];
  float s = a * a + b * b + c * c + d * d;
#pragma unroll
  for (int off = 32; off; off >>= 1) s += __shfl_xor(s, off, 64);
  if (lane == 0) rn[row] = fmaxf(sqrtf(s), 1e-8f);
}

// ---------------------------------------------------------------------------
// Phase B: sequential GRU scan, HYBRID matrix+vector pipes. ONE block,
// 512 threads (8 waves, 2/SIMD).
//
// Gates r,z (512 rows): MFMA matvec, round-4 structure with 4 tiles
//   ({r,z} x col-half) x 8 k-chunks = 32 mfma_16x16x32_f16 per wave/step.
//   Weights resident as A-fragments (4x8 half8 = 128 regs, AGPR-native for
//   MFMA). h broadcast into all 16 B-columns -> every C column equals y;
//   SEL8 tree gives lane its column's y_r,y_z.
// Gate n (256 rows): VALU fdot2, round-5 structure (kq=lane&3 k-quarter,
//   2 columns/thread) -> Wn[2][32] = only 64 ARCH VGPRs (under the 128-arch
//   cap, so no v_accvgpr_read per MAC -- the round-3/5 killer). Quad DPP
//   reduce, then a SAME-WAVE LDS exchange (write y_n[2], read y_n[cm]; each
//   wave's 32 columns are self-contained; DS ops in-order within a wave, no
//   barrier) hands y_n to the MFMA column owner.
// The two streams are data-independent until the gate math, so the wave
// interleaves MFMA and VALU issue and the pipes overlap (m114).
// Per-SIMD budget: max(matrix 64x19.4=1242, VALU ~700) + ~300 sync.
// ONE barrier per step; h double-buffered f16 in LDS.
// ---------------------------------------------------------------------------
__global__ __launch_bounds__(512, 2) void gru_kernel(
    const float* __restrict__ Whh, const float* __restrict__ bhh,
    const float* __restrict__ xw, float* __restrict__ zout)
{
  __shared__ __align__(16) _Float16 hbuf[2][HID];  // double-buffered h
  __shared__ __align__(16) float ynbuf[HID];       // per-step y_n exchange
  const int i    = threadIdx.x;
  const int w    = i >> 6;
  const int lane = i & 63;
  const int g    = lane >> 4;          // C-rows g*4..g*4+3; B k-sub g*8..+8
  const int r16  = lane & 15;          // A-fragment row within a 16-row tile
  const int jsel = lane & 7;           // (t2,reg) this lane finalizes
  const int cm   = w * 32 + (jsel >> 2) * 16 + g * 4 + (jsel & 3);
  const bool writer = r16 < 8;         // one finalizer copy publishes
  // VALU n-gate assignment: k-quarter kq, column pair (c0,c1)
  const int kq = lane & 3;
  const int cp = w * 16 + (lane >> 2);
  const int c0 = 2 * cp, c1 = c0 + 1;

  // --- resident A-fragments for gates r,z: [G*2+t2][kc], 128 regs ---
  half8_t A[4][8];
#pragma unroll
  for (int G = 0; G < 2; ++G)
#pragma unroll
    for (int t2 = 0; t2 < 2; ++t2) {
      const int row = G * 256 + w * 32 + t2 * 16 + r16;
      const float* wp = Whh + (size_t)row * 256 + g * 8;
#pragma unroll
      for (int kc = 0; kc < 8; ++kc) {
        const float4* w4 = (const float4*)(wp + kc * 32);
        float4 u = w4[0], v = w4[1];
        half8_t f;
        f[0] = (_Float16)u.x; f[1] = (_Float16)u.y;
        f[2] = (_Float16)u.z; f[3] = (_Float16)u.w;
        f[4] = (_Float16)v.x; f[5] = (_Float16)v.y;
        f[6] = (_Float16)v.z; f[7] = (_Float16)v.w;
        A[G * 2 + t2][kc] = f;
      }
    }

  // --- resident n-gate weights: rows 512+c0, 512+c1, k-quarter kq (64 arch) ---
  half2_t Wn[2][32];
#pragma unroll
  for (int cc = 0; cc < 2; ++cc) {
    const int row = 512 + c0 + cc;
    const float4* wp = (const float4*)(Whh + (size_t)row * 256 + kq * 64);
#pragma unroll
    for (int m = 0; m < 16; ++m) {
      float4 a = wp[m];
      half2_t p0; p0.x = (_Float16)a.x; p0.y = (_Float16)a.y;
      half2_t p1; p1.x = (_Float16)a.z; p1.y = (_Float16)a.w;
      Wn[cc][2 * m]     = p0;
      Wn[cc][2 * m + 1] = p1;
    }
  }

  const float br  = bhh[cm];
  const float bz  = bhh[256 + cm];
  const float bnn = bhh[512 + cm];

  if (i < HID) hbuf[0][i] = (_Float16)0.0f;
  __syncthreads();

  float hreg = 0.0f;   // h[cm], tracked by both r16-parity copies
  float xr0 = xw[cm], xz0 = xw[256 + cm], xn0 = xw[512 + cm];

  const f32x4 zf = {0.f, 0.f, 0.f, 0.f};

  for (int s = 0; s < SEQ; ++s) {
    // issue next step's xW loads now (latency hidden behind the MFMAs)
    const size_t bnext = (size_t)(s + 1 < SEQ ? s + 1 : s) * G3;
    float xr1 = xw[bnext + cm], xz1 = xw[bnext + 256 + cm], xn1 = xw[bnext + 512 + cm];

    const _Float16* hc = hbuf[s & 1];

    // --- MFMA stream: 4 tiles x 8 k-chunks, depth-1 B-frag prefetch ---
    f32x4 acc[4];
    half8_t bq = *(const half8_t*)(hc + g * 8);            // kc = 0
    half8_t bp = *(const half8_t*)(hc + 32 + g * 8);       // kc = 1
#pragma unroll
    for (int t = 0; t < 4; ++t)
      acc[t] = __builtin_amdgcn_mfma_f32_16x16x32_f16(A[t][0], bq, zf, 0, 0, 0);
    bq = bp;
#pragma unroll
    for (int kc = 1; kc < 8; ++kc) {
      half8_t bn2;
      if (kc < 7) bn2 = *(const half8_t*)(hc + (kc + 1) * 32 + g * 8);
#pragma unroll
      for (int t = 0; t < 4; ++t)
        acc[t] = __builtin_amdgcn_mfma_f32_16x16x32_f16(A[t][kc], bq, acc[t], 0, 0, 0);
      if (kc < 7) bq = bn2;
    }

    // --- VALU stream: n-gate quarter-dots (bank-rotated read order) ---
    const uint4* hq = (const uint4*)hc + kq * 8;   // 8 x 16B = this k-quarter
    float a0 = 0.f, a1 = 0.f;
#pragma unroll
    for (int m = 0; m < 8; ++m) {
      const int mm = (m + 2 * kq) & 7;   // disjoint bank groups across kq
      uint4 cur = hq[mm];
      half2_t hx = h2_from_u32(cur.x), hy = h2_from_u32(cur.y);
      half2_t hz = h2_from_u32(cur.z), hw = h2_from_u32(cur.w);
      a0 = fdot2(Wn[0][4 * mm + 0], hx, a0);
      a1 = fdot2(Wn[1][4 * mm + 0], hx, a1);
      a0 = fdot2(Wn[0][4 * mm + 1], hy, a0);
      a1 = fdot2(Wn[1][4 * mm + 1], hy, a1);
      a0 = fdot2(Wn[0][4 * mm + 2], hz, a0);
      a1 = fdot2(Wn[1][4 * mm + 2], hz, a1);
      a0 = fdot2(Wn[0][4 * mm + 3], hw, a0);
      a1 = fdot2(Wn[1][4 * mm + 3], hw, a1);
    }
    float yn0 = quad_sum(a0), yn1 = quad_sum(a1);

    // --- same-wave exchange: quad leader publishes its pair, owner reads ---
    if (kq == 0) {
      float2 yv; yv.x = yn0; yv.y = yn1;
      *(float2*)(ynbuf + c0) = yv;
    }
    float yn = ynbuf[cm];   // same wave wrote cols w*32..+31; DS in-order

    // --- select this lane's y_r,y_z from the replicated C candidates ---
#define SEL8(x, y, out) do {                       \
      float p0 = s0 ? (x)[1] : (x)[0];             \
      float p1 = s0 ? (x)[3] : (x)[2];             \
      float p2 = s0 ? (y)[1] : (y)[0];             \
      float p3 = s0 ? (y)[3] : (y)[2];             \
      float q0 = s1 ? p1 : p0;                     \
      float q1 = s1 ? p3 : p2;                     \
      out = s2 ? q1 : q0;                          \
    } while (0)
    const bool s0 = (jsel & 1) != 0, s1 = (jsel & 2) != 0, s2 = (jsel & 4) != 0;
    float yr, yz;
    SEL8(acc[0], acc[1], yr);
    SEL8(acc[2], acc[3], yz);
#undef SEL8

    // --- gate math for the one owned column (f32) ---
    float rg = sigmoidf_fast(yr + br + xr0);
    float zg = sigmoidf_fast(yz + bz + xz0);
    float ng = tanhf_fast(xn0 + rg * (yn + bnn));
    hreg = (1.0f - zg) * ng + zg * hreg;

    if (writer) {
      hbuf[(s + 1) & 1][cm] = (_Float16)hreg;
      zout[(size_t)s * HID + cm] = hreg;
    }
    __syncthreads();
    xr0 = xr1; xz0 = xz1; xn0 = xn1;
  }
}

// ---------------------------------------------------------------------------
// Phase C: NCE loss + accuracy. One block per t, 4 waves = 4 timespans.
// Reads f32 z straight from d_out.
// ---------------------------------------------------------------------------
__global__ __launch_bounds__(256) void cpc_kernel(
    const float* __restrict__ x, const float* __restrict__ zf,
    const float* __restrict__ rn, float* __restrict__ accum)
{
  __shared__ float zsh[HID];
  __shared__ float wsum[4];
  __shared__ float nce_s[4], acc_s[4];
  const int tt = TSTART + blockIdx.x;
  const int i = threadIdx.x;
  const int wave = i >> 6, lane = i & 63;

  float zi = zf[(size_t)tt * HID + i];
  zsh[i] = zi;
  float p = zi * zi;
#pragma unroll
  for (int off = 32; off; off >>= 1) p += __shfl_xor(p, off, 64);
  if (lane == 0) wsum[wave] = p;
  __syncthreads();
  float zn = fmaxf(sqrtf(wsum[0] + wsum[1] + wsum[2] + wsum[3]), 1e-8f);

  float z0 = zsh[lane], z1 = zsh[lane + 64], z2 = zsh[lane + 128], z3 = zsh[lane + 192];
  const int base = tt + wave + 1;   // pos index for timespan (wave+1)

  float tot[10];
#pragma unroll
  for (int n = 0; n < 10; ++n) {
    int idx = base + (n > 0 ? (NEGD + n - 1) : 0);
    const float* xr = x + (size_t)idx * HID;
    float q = xr[lane] * z0 + xr[lane + 64] * z1 + xr[lane + 128] * z2 + xr[lane + 192] * z3;
#pragma unroll
    for (int off = 32; off; off >>= 1) q += __shfl_xor(q, off, 64);
    tot[n] = q / (rn[idx] * zn);
  }
  float m = tot[0];
#pragma unroll
  for (int n = 1; n < 10; ++n) m = fmaxf(m, tot[n]);
  float se = 0.f;
#pragma unroll
  for (int n = 0; n < 10; ++n) se += expf(tot[n] - m);
  float logp0 = (tot[0] - m) - logf(se);
  float accv = (tot[0] >= m) ? 1.0f : 0.0f;  // argmax==0 iff tot[0] is the max

  if (lane == 0) { nce_s[wave] = -logp0; acc_s[wave] = accv; }
  __syncthreads();
  if (i == 0) {
    atomicAdd(accum,     nce_s[0] + nce_s[1] + nce_s[2] + nce_s[3]);
    atomicAdd(accum + 1, acc_s[0] + acc_s[1] + acc_s[2] + acc_s[3]);
  }
}

__global__ void fin_kernel(const float* __restrict__ accum,
                           float* __restrict__ out)
{
  if (threadIdx.x == 0) {
    out[(size_t)SEQ * HID]     = accum[0] / DENOMF;   // nce
    out[(size_t)SEQ * HID + 1] = accum[1] / DENOMF;   // acc
  }
}

// ---------------------------------------------------------------------------
extern "C" void kernel_launch(void* const* d_in, const int* in_sizes, int n_in,
                              void* d_out, int out_size, void* d_ws, size_t ws_size,
                              hipStream_t stream)
{
  // Inputs are f32 (reference dtypes). Output f32: z [SEQ*HID] | nce | acc.
  const float* data = (const float*)d_in[0];
  const float* Wih  = (const float*)d_in[1];
  const float* Whh  = (const float*)d_in[2];
  const float* bih  = (const float*)d_in[3];
  const float* bhh  = (const float*)d_in[4];
  float* out = (float*)d_out;

  // ws layout: xw f32 [SEQ*768] 25.17MB | rn f32 [SEQ] | accum f32 [2]
  char* p = (char*)d_ws;
  float* xw    = (float*)p;  p += (size_t)SEQ * G3 * sizeof(float);
  float* rn    = (float*)p;  p += (size_t)SEQ * sizeof(float);
  float* accum = (float*)p;

  init_kernel<<<1, 64, 0, stream>>>(accum);
  xw_kernel<<<dim3(256, 3), 256, 0, stream>>>(data, Wih, bih, xw);
  rnorm_kernel<<<SEQ / 4, 256, 0, stream>>>(data, rn);
  gru_kernel<<<1, 512, 0, stream>>>(Whh, bhh, xw, out);
  cpc_kernel<<<TCNT, 256, 0, stream>>>(data, out, rn, accum);
  fin_kernel<<<1, 1, 0, stream>>>(accum, out);
}

// Round 7
// 11375.379 us; speedup vs baseline: 5.6798x; 5.6798x over previous
//
#include <hip/hip_runtime.h>

// Problem constants (from reference)
#define SEQ   8192
#define HID   256
#define G3    768      // 3*HID
#define TSTART 1024    // SEQ/8
#define NEGD  1365     // SEQ/6
#define TCNT  5791     // (SEQ - 10 - NEGD - 4 + 2) - TSTART
#define DENOMF 23164.0f // TCNT*4

typedef _Float16 half2_t __attribute__((ext_vector_type(2)));
typedef _Float16 half8_t __attribute__((ext_vector_type(8)));
typedef float    f32x4  __attribute__((ext_vector_type(4)));

__device__ __forceinline__ float fdot2(half2_t a, half2_t b, float c) {
#if __has_builtin(__builtin_amdgcn_fdot2)
  return __builtin_amdgcn_fdot2(a, b, c, false);
#else
  return c + (float)a.x * (float)b.x + (float)a.y * (float)b.y;
#endif
}

__device__ __forceinline__ half2_t h2_from_u32(unsigned int u) {
  return __builtin_bit_cast(half2_t, u);
}

__device__ __forceinline__ float sigmoidf_fast(float x) {
  return 1.0f / (1.0f + __expf(-x));
}
// tanh via sigmoid form: safe at both extremes (exp under/overflow -> +-1)
__device__ __forceinline__ float tanhf_fast(float x) {
  return 2.0f / (1.0f + __expf(-2.0f * x)) - 1.0f;
}

// ---------------------------------------------------------------------------
// init: zero the loss accumulators (ws is poisoned 0xAA every call)
// ---------------------------------------------------------------------------
__global__ void init_kernel(float* accum) {
  if (threadIdx.x < 2) accum[threadIdx.x] = 0.0f;
}

// ---------------------------------------------------------------------------
// Phase A: xW = data @ Wih^T + bih -> f32 [SEQ][768]. All f32.
// grid (256, 3), block 256. Thread owns output col o; 32-row x-tile in LDS.
// ---------------------------------------------------------------------------
__global__ __launch_bounds__(256) void xw_kernel(
    const float* __restrict__ data, const float* __restrict__ Wih,
    const float* __restrict__ bih, float* __restrict__ xw)
{
  __shared__ float4 xs4[32 * 64];   // 32 rows x 256 f32 = 32 KB
  const int o  = blockIdx.y * 256 + threadIdx.x;
  const int m0 = blockIdx.x * 32;

  float* xsf = (float*)xs4;
  for (int r = 0; r < 32; ++r)
    xsf[r * 256 + threadIdx.x] = data[(size_t)(m0 + r) * 256 + threadIdx.x];
  __syncthreads();

  const float b = bih[o];
  float acc[32];
#pragma unroll
  for (int r = 0; r < 32; ++r) acc[r] = b;

  const float4* wrow = (const float4*)(Wih + (size_t)o * 256);
  for (int kc = 0; kc < 4; ++kc) {
    float4 w[16];
#pragma unroll
    for (int j = 0; j < 16; ++j) w[j] = wrow[kc * 16 + j];
#pragma unroll
    for (int r = 0; r < 32; ++r) {
      const float4* xr = xs4 + r * 64 + kc * 16;
      float a0 = 0.f, a1 = 0.f, a2 = 0.f, a3 = 0.f;
#pragma unroll
      for (int j = 0; j < 4; ++j) {
        float4 x0 = xr[4 * j + 0], x1 = xr[4 * j + 1];
        float4 x2 = xr[4 * j + 2], x3 = xr[4 * j + 3];
        float4 w0 = w[4 * j + 0], w1 = w[4 * j + 1];
        float4 w2 = w[4 * j + 2], w3 = w[4 * j + 3];
        a0 = fmaf(w0.x, x0.x, fmaf(w0.y, x0.y, fmaf(w0.z, x0.z, fmaf(w0.w, x0.w, a0))));
        a1 = fmaf(w1.x, x1.x, fmaf(w1.y, x1.y, fmaf(w1.z, x1.z, fmaf(w1.w, x1.w, a1))));
        a2 = fmaf(w2.x, x2.x, fmaf(w2.y, x2.y, fmaf(w2.z, x2.z, fmaf(w2.w, x2.w, a2))));
        a3 = fmaf(w3.x, x3.x, fmaf(w3.y, x3.y, fmaf(w3.z, x3.z, fmaf(w3.w, x3.w, a3))));
      }
      acc[r] += (a0 + a1) + (a2 + a3);
    }
  }
  for (int r = 0; r < 32; ++r)
    xw[(size_t)(m0 + r) * G3 + o] = acc[r];
}

// ---------------------------------------------------------------------------
// data row norms: one wave per row (f32 data)
// ---------------------------------------------------------------------------
__global__ __launch_bounds__(256) void rnorm_kernel(
    const float* __restrict__ data, float* __restrict__ rn)
{
  int wave = threadIdx.x >> 6, lane = threadIdx.x & 63;
  int row = blockIdx.x * 4 + wave;
  const float* xr = data + (size_t)row * HID;
  float a = xr[lane], b = xr[lane + 64], c = xr[lane + 128], d = xr[lane + 192];
  float s = a * a + b * b + c * c + d * d;
#pragma unroll
  for (int off = 32; off; off >>= 1) s += __shfl_xor(s, off, 64);
  if (lane == 0) rn[row] = fmaxf(sqrtf(s), 1e-8f);
}

// ---------------------------------------------------------------------------
// Phase B: sequential GRU scan, HYBRID matrix+vector pipes, v2. ONE block,
// 512 threads (8 waves, 2/SIMD).
//
// v2 fixes round 6's 10x regression, which was rule-#20 scratch: the
// bank-rotated Wn[cc][4*mm+j] used a RUNTIME index -> Wn went to local
// memory, every fdot2 paid a scratch round-trip. Here ALL register-array
// indices are compile-time constants in fully unrolled loops, and the
// n-gate stream reads NO LDS of its own: it consumes the MFMA B-fragments.
//
// Gates r,z (512 rows): MFMA matvec (round-4-verified): 4 tiles
//   ({r,z} x col-half) x 8 k-chunks = 32 mfma_16x16x32_f16/wave/step,
//   A-fragments resident (4x8 half8 = 128 regs, AGPR-native). h broadcast
//   into all 16 B-columns; SEL8 tree -> lane's y_r,y_z.
// Gate n (256 rows): VALU fdot2 on the SAME bq fragments. Lane's B-frags
//   cover k in {32kc + 8g + j} (g = lane>>4), a partition of [0,256) over
//   the 4 g-groups. Wn[2][32] (64 arch VGPRs) holds rows 512+c0,512+c1 at
//   exactly those k. Cross-g reduce = shfl_xor 16 + 32 (harness-proven);
//   y_n hops to the MFMA column owner via a same-wave LDS exchange
//   (round-6-verified correct; DS ops in-order within a wave, no barrier).
// Per-SIMD budget: MFMA 64x19.4=1242 cyc, VALU ~540 cyc overlapped (m114),
// serial tail ~250. ONE barrier per step; h double-buffered f16 in LDS.
// ---------------------------------------------------------------------------
__global__ __launch_bounds__(512, 2) void gru_kernel(
    const float* __restrict__ Whh, const float* __restrict__ bhh,
    const float* __restrict__ xw, float* __restrict__ zout)
{
  __shared__ __align__(16) _Float16 hbuf[2][HID];  // double-buffered h
  __shared__ __align__(16) float ynbuf[HID];       // per-step y_n exchange
  const int i    = threadIdx.x;
  const int w    = i >> 6;
  const int lane = i & 63;
  const int g    = lane >> 4;          // C-rows g*4..g*4+3; B k-sub g*8..+8
  const int r16  = lane & 15;          // A-fragment row within a 16-row tile
  const int jsel = lane & 7;           // (t2,reg) this lane finalizes
  const int cm   = w * 32 + (jsel >> 2) * 16 + g * 4 + (jsel & 3);
  const bool writer = r16 < 8;         // one finalizer copy publishes
  // VALU n-gate column pair (one per r16 within the wave)
  const int c0 = 2 * (w * 16 + r16), c1 = c0 + 1;

  // --- resident A-fragments for gates r,z: [G*2+t2][kc], 128 regs ---
  half8_t A[4][8];
#pragma unroll
  for (int G = 0; G < 2; ++G)
#pragma unroll
    for (int t2 = 0; t2 < 2; ++t2) {
      const int row = G * 256 + w * 32 + t2 * 16 + r16;
      const float* wp = Whh + (size_t)row * 256 + g * 8;
#pragma unroll
      for (int kc = 0; kc < 8; ++kc) {
        const float4* w4 = (const float4*)(wp + kc * 32);
        float4 u = w4[0], v = w4[1];
        half8_t f;
        f[0] = (_Float16)u.x; f[1] = (_Float16)u.y;
        f[2] = (_Float16)u.z; f[3] = (_Float16)u.w;
        f[4] = (_Float16)v.x; f[5] = (_Float16)v.y;
        f[6] = (_Float16)v.z; f[7] = (_Float16)v.w;
        A[G * 2 + t2][kc] = f;
      }
    }

  // --- resident n-gate weights matching the B-frag k-layout ---
  // Wn[cc][kc*4 + jp] covers k = 32*kc + 8*g + 2*jp (+1). 64 arch VGPRs.
  half2_t Wn[2][32];
#pragma unroll
  for (int cc = 0; cc < 2; ++cc) {
    const float* wp = Whh + (size_t)(512 + c0 + cc) * 256 + g * 8;
#pragma unroll
    for (int kc = 0; kc < 8; ++kc) {
      const float4* w4 = (const float4*)(wp + kc * 32);
      float4 u = w4[0], v = w4[1];
      half2_t p0; p0.x = (_Float16)u.x; p0.y = (_Float16)u.y;
      half2_t p1; p1.x = (_Float16)u.z; p1.y = (_Float16)u.w;
      half2_t p2; p2.x = (_Float16)v.x; p2.y = (_Float16)v.y;
      half2_t p3; p3.x = (_Float16)v.z; p3.y = (_Float16)v.w;
      Wn[cc][kc * 4 + 0] = p0;
      Wn[cc][kc * 4 + 1] = p1;
      Wn[cc][kc * 4 + 2] = p2;
      Wn[cc][kc * 4 + 3] = p3;
    }
  }

  const float br  = bhh[cm];
  const float bz  = bhh[256 + cm];
  const float bnn = bhh[512 + cm];

  if (i < HID) hbuf[0][i] = (_Float16)0.0f;
  __syncthreads();

  float hreg = 0.0f;   // h[cm], tracked by both r16-parity copies
  float xr0 = xw[cm], xz0 = xw[256 + cm], xn0 = xw[512 + cm];

  const f32x4 zf = {0.f, 0.f, 0.f, 0.f};

  for (int s = 0; s < SEQ; ++s) {
    // issue next step's xW loads now (latency hidden behind the MFMAs)
    const size_t bnext = (size_t)(s + 1 < SEQ ? s + 1 : s) * G3;
    float xr1 = xw[bnext + cm], xz1 = xw[bnext + 256 + cm], xn1 = xw[bnext + 512 + cm];

    const _Float16* hc = hbuf[s & 1];

    // --- fused MFMA (r,z) + VALU (n) streams over the same B-frags ---
    f32x4 acc[4];
    float a0 = 0.f, a1 = 0.f;
    half8_t bq = *(const half8_t*)(hc + g * 8);            // kc = 0
    half8_t bp = *(const half8_t*)(hc + 32 + g * 8);       // kc = 1
    {
      uint4 bu = __builtin_bit_cast(uint4, bq);
      half2_t hx = h2_from_u32(bu.x), hy = h2_from_u32(bu.y);
      half2_t hz = h2_from_u32(bu.z), hw = h2_from_u32(bu.w);
#pragma unroll
      for (int t = 0; t < 4; ++t)
        acc[t] = __builtin_amdgcn_mfma_f32_16x16x32_f16(A[t][0], bq, zf, 0, 0, 0);
      a0 = fdot2(Wn[0][0], hx, a0);
      a1 = fdot2(Wn[1][0], hx, a1);
      a0 = fdot2(Wn[0][1], hy, a0);
      a1 = fdot2(Wn[1][1], hy, a1);
      a0 = fdot2(Wn[0][2], hz, a0);
      a1 = fdot2(Wn[1][2], hz, a1);
      a0 = fdot2(Wn[0][3], hw, a0);
      a1 = fdot2(Wn[1][3], hw, a1);
    }
    bq = bp;
#pragma unroll
    for (int kc = 1; kc < 8; ++kc) {
      half8_t bn2;
      if (kc < 7) bn2 = *(const half8_t*)(hc + (kc + 1) * 32 + g * 8);
      uint4 bu = __builtin_bit_cast(uint4, bq);
      half2_t hx = h2_from_u32(bu.x), hy = h2_from_u32(bu.y);
      half2_t hz = h2_from_u32(bu.z), hw = h2_from_u32(bu.w);
#pragma unroll
      for (int t = 0; t < 4; ++t)
        acc[t] = __builtin_amdgcn_mfma_f32_16x16x32_f16(A[t][kc], bq, acc[t], 0, 0, 0);
      a0 = fdot2(Wn[0][kc * 4 + 0], hx, a0);
      a1 = fdot2(Wn[1][kc * 4 + 0], hx, a1);
      a0 = fdot2(Wn[0][kc * 4 + 1], hy, a0);
      a1 = fdot2(Wn[1][kc * 4 + 1], hy, a1);
      a0 = fdot2(Wn[0][kc * 4 + 2], hz, a0);
      a1 = fdot2(Wn[1][kc * 4 + 2], hz, a1);
      a0 = fdot2(Wn[0][kc * 4 + 3], hw, a0);
      a1 = fdot2(Wn[1][kc * 4 + 3], hw, a1);
      if (kc < 7) bq = bn2;
    }

    // --- cross-g reduce (partition of k over the 4 g-groups) ---
    a0 += __shfl_xor(a0, 16, 64);
    a0 += __shfl_xor(a0, 32, 64);
    a1 += __shfl_xor(a1, 16, 64);
    a1 += __shfl_xor(a1, 32, 64);

    // --- same-wave exchange: g==0 copy publishes its pair, owner reads ---
    if (g == 0) {
      float2 yv; yv.x = a0; yv.y = a1;
      *(float2*)(ynbuf + c0) = yv;
    }
    float yn = ynbuf[cm];   // same wave wrote cols w*32..+31; DS in-order

    // --- select this lane's y_r,y_z from the replicated C candidates ---
#define SEL8(x, y, out) do {                       \
      float p0 = s0 ? (x)[1] : (x)[0];             \
      float p1 = s0 ? (x)[3] : (x)[2];             \
      float p2 = s0 ? (y)[1] : (y)[0];             \
      float p3 = s0 ? (y)[3] : (y)[2];             \
      float q0 = s1 ? p1 : p0;                     \
      float q1 = s1 ? p3 : p2;                     \
      out = s2 ? q1 : q0;                          \
    } while (0)
    const bool s0 = (jsel & 1) != 0, s1 = (jsel & 2) != 0, s2 = (jsel & 4) != 0;
    float yr, yz;
    SEL8(acc[0], acc[1], yr);
    SEL8(acc[2], acc[3], yz);
#undef SEL8

    // --- gate math for the one owned column (f32) ---
    float rg = sigmoidf_fast(yr + br + xr0);
    float zg = sigmoidf_fast(yz + bz + xz0);
    float ng = tanhf_fast(xn0 + rg * (yn + bnn));
    hreg = (1.0f - zg) * ng + zg * hreg;

    if (writer) {
      hbuf[(s + 1) & 1][cm] = (_Float16)hreg;
      zout[(size_t)s * HID + cm] = hreg;
    }
    __syncthreads();
    xr0 = xr1; xz0 = xz1; xn0 = xn1;
  }
}

// ---------------------------------------------------------------------------
// Phase C: NCE loss + accuracy. One block per t, 4 waves = 4 timespans.
// Reads f32 z straight from d_out.
// ---------------------------------------------------------------------------
__global__ __launch_bounds__(256) void cpc_kernel(
    const float* __restrict__ x, const float* __restrict__ zf,
    const float* __restrict__ rn, float* __restrict__ accum)
{
  __shared__ float zsh[HID];
  __shared__ float wsum[4];
  __shared__ float nce_s[4], acc_s[4];
  const int tt = TSTART + blockIdx.x;
  const int i = threadIdx.x;
  const int wave = i >> 6, lane = i & 63;

  float zi = zf[(size_t)tt * HID + i];
  zsh[i] = zi;
  float p = zi * zi;
#pragma unroll
  for (int off = 32; off; off >>= 1) p += __shfl_xor(p, off, 64);
  if (lane == 0) wsum[wave] = p;
  __syncthreads();
  float zn = fmaxf(sqrtf(wsum[0] + wsum[1] + wsum[2] + wsum[3]), 1e-8f);

  float z0 = zsh[lane], z1 = zsh[lane + 64], z2 = zsh[lane + 128], z3 = zsh[lane + 192];
  const int base = tt + wave + 1;   // pos index for timespan (wave+1)

  float tot[10];
#pragma unroll
  for (int n = 0; n < 10; ++n) {
    int idx = base + (n > 0 ? (NEGD + n - 1) : 0);
    const float* xr = x + (size_t)idx * HID;
    float q = xr[lane] * z0 + xr[lane + 64] * z1 + xr[lane + 128] * z2 + xr[lane + 192] * z3;
#pragma unroll
    for (int off = 32; off; off >>= 1) q += __shfl_xor(q, off, 64);
    tot[n] = q / (rn[idx] * zn);
  }
  float m = tot[0];
#pragma unroll
  for (int n = 1; n < 10; ++n) m = fmaxf(m, tot[n]);
  float se = 0.f;
#pragma unroll
  for (int n = 0; n < 10; ++n) se += expf(tot[n] - m);
  float logp0 = (tot[0] - m) - logf(se);
  float accv = (tot[0] >= m) ? 1.0f : 0.0f;  // argmax==0 iff tot[0] is the max

  if (lane == 0) { nce_s[wave] = -logp0; acc_s[wave] = accv; }
  __syncthreads();
  if (i == 0) {
    atomicAdd(accum,     nce_s[0] + nce_s[1] + nce_s[2] + nce_s[3]);
    atomicAdd(accum + 1, acc_s[0] + acc_s[1] + acc_s[2] + acc_s[3]);
  }
}

__global__ void fin_kernel(const float* __restrict__ accum,
                           float* __restrict__ out)
{
  if (threadIdx.x == 0) {
    out[(size_t)SEQ * HID]     = accum[0] / DENOMF;   // nce
    out[(size_t)SEQ * HID + 1] = accum[1] / DENOMF;   // acc
  }
}

// ---------------------------------------------------------------------------
extern "C" void kernel_launch(void* const* d_in, const int* in_sizes, int n_in,
                              void* d_out, int out_size, void* d_ws, size_t ws_size,
                              hipStream_t stream)
{
  // Inputs are f32 (reference dtypes). Output f32: z [SEQ*HID] | nce | acc.
  const float* data = (const float*)d_in[0];
  const float* Wih  = (const float*)d_in[1];
  const float* Whh  = (const float*)d_in[2];
  const float* bih  = (const float*)d_in[3];
  const float* bhh  = (const float*)d_in[4];
  float* out = (float*)d_out;

  // ws layout: xw f32 [SEQ*768] 25.17MB | rn f32 [SEQ] | accum f32 [2]
  char* p = (char*)d_ws;
  float* xw    = (float*)p;  p += (size_t)SEQ * G3 * sizeof(float);
  float* rn    = (float*)p;  p += (size_t)SEQ * sizeof(float);
  float* accum = (float*)p;

  init_kernel<<<1, 64, 0, stream>>>(accum);
  xw_kernel<<<dim3(256, 3), 256, 0, stream>>>(data, Wih, bih, xw);
  rnorm_kernel<<<SEQ / 4, 256, 0, stream>>>(data, rn);
  gru_kernel<<<1, 512, 0, stream>>>(Whh, bhh, xw, out);
  cpc_kernel<<<TCNT, 256, 0, stream>>>(data, out, rn, accum);
  fin_kernel<<<1, 1, 0, stream>>>(accum, out);
}

// Round 9
// 11285.722 us; speedup vs baseline: 5.7249x; 1.0079x over previous
//
#include <hip/hip_runtime.h>

// Problem constants (from reference)
#define SEQ   8192
#define HID   256
#define G3    768      // 3*HID
#define TSTART 1024    // SEQ/8
#define NEGD  1365     // SEQ/6
#define TCNT  5791     // (SEQ - 10 - NEGD - 4 + 2) - TSTART
#define DENOMF 23164.0f // TCNT*4

typedef _Float16 half8_t __attribute__((ext_vector_type(8)));
typedef float    f32x4  __attribute__((ext_vector_type(4)));

__device__ __forceinline__ float sigmoidf_fast(float x) {
  return 1.0f / (1.0f + __expf(-x));
}
// tanh via sigmoid form: safe at both extremes (exp under/overflow -> +-1)
__device__ __forceinline__ float tanhf_fast(float x) {
  return 2.0f / (1.0f + __expf(-2.0f * x)) - 1.0f;
}

// ---------------------------------------------------------------------------
// init: zero the loss accumulators (ws is poisoned 0xAA every call)
// ---------------------------------------------------------------------------
__global__ void init_kernel(float* accum) {
  if (threadIdx.x < 2) accum[threadIdx.x] = 0.0f;
}

// ---------------------------------------------------------------------------
// Phase A: xW = data @ Wih^T + bih -> f32 [SEQ][768]. All f32.
// grid (256, 3), block 256. Thread owns output col o; 32-row x-tile in LDS.
// ---------------------------------------------------------------------------
__global__ __launch_bounds__(256) void xw_kernel(
    const float* __restrict__ data, const float* __restrict__ Wih,
    const float* __restrict__ bih, float* __restrict__ xw)
{
  __shared__ float4 xs4[32 * 64];   // 32 rows x 256 f32 = 32 KB
  const int o  = blockIdx.y * 256 + threadIdx.x;
  const int m0 = blockIdx.x * 32;

  float* xsf = (float*)xs4;
  for (int r = 0; r < 32; ++r)
    xsf[r * 256 + threadIdx.x] = data[(size_t)(m0 + r) * 256 + threadIdx.x];
  __syncthreads();

  const float b = bih[o];
  float acc[32];
#pragma unroll
  for (int r = 0; r < 32; ++r) acc[r] = b;

  const float4* wrow = (const float4*)(Wih + (size_t)o * 256);
  for (int kc = 0; kc < 4; ++kc) {
    float4 w[16];
#pragma unroll
    for (int j = 0; j < 16; ++j) w[j] = wrow[kc * 16 + j];
#pragma unroll
    for (int r = 0; r < 32; ++r) {
      const float4* xr = xs4 + r * 64 + kc * 16;
      float a0 = 0.f, a1 = 0.f, a2 = 0.f, a3 = 0.f;
#pragma unroll
      for (int j = 0; j < 4; ++j) {
        float4 x0 = xr[4 * j + 0], x1 = xr[4 * j + 1];
        float4 x2 = xr[4 * j + 2], x3 = xr[4 * j + 3];
        float4 w0 = w[4 * j + 0], w1 = w[4 * j + 1];
        float4 w2 = w[4 * j + 2], w3 = w[4 * j + 3];
        a0 = fmaf(w0.x, x0.x, fmaf(w0.y, x0.y, fmaf(w0.z, x0.z, fmaf(w0.w, x0.w, a0))));
        a1 = fmaf(w1.x, x1.x, fmaf(w1.y, x1.y, fmaf(w1.z, x1.z, fmaf(w1.w, x1.w, a1))));
        a2 = fmaf(w2.x, x2.x, fmaf(w2.y, x2.y, fmaf(w2.z, x2.z, fmaf(w2.w, x2.w, a2))));
        a3 = fmaf(w3.x, x3.x, fmaf(w3.y, x3.y, fmaf(w3.z, x3.z, fmaf(w3.w, x3.w, a3))));
      }
      acc[r] += (a0 + a1) + (a2 + a3);
    }
  }
  for (int r = 0; r < 32; ++r)
    xw[(size_t)(m0 + r) * G3 + o] = acc[r];
}

// ---------------------------------------------------------------------------
// data row norms: one wave per row (f32 data)
// ---------------------------------------------------------------------------
__global__ __launch_bounds__(256) void rnorm_kernel(
    const float* __restrict__ data, float* __restrict__ rn)
{
  int wave = threadIdx.x >> 6, lane = threadIdx.x & 63;
  int row = blockIdx.x * 4 + wave;
  const float* xr = data + (size_t)row * HID;
  float a = xr[lane], b = xr[lane + 64], c = xr[lane + 128], d = xr[lane + 192];
  float s = a * a + b * b + c * c + d * d;
#pragma unroll
  for (int off = 32; off; off >>= 1) s += __shfl_xor(s, off, 64);
  if (lane == 0) rn[row] = fmaxf(sqrtf(s), 1e-8f);
}

// ---------------------------------------------------------------------------
// Phase B: sequential GRU scan via MFMA matvec. ONE block, 1024 threads
// (16 waves, 4/SIMD) -- the round-4-verified structure (7722us, passed)
// re-parameterized for higher occupancy.
//
// Why: round-4 counters showed MFMA busy ~68% of the 2262-cyc step; the
// 2-waves/SIMD config let the matrix pipe idle whenever both waves were in
// their serial tails (B-frag loads, SEL, gate math, publish, barrier).
// Total matrix work per step is fixed (384 MFMAs/CU); 4 waves/SIMD overlap
// the tails. Each wave now owns 16 output columns x 3 gates = 3 row-tiles
// of 16, K = 8 chunks of 32 -> 24 mfma_16x16x32_f16 per wave per step.
//
// Per-wave registers: AGPR = A[3][8] half8 (96) + acc[3] f32x4 (12) = 108;
// arch = rolling B-frag prefetch (16) + misc -- both under the 128/wave
// budget a 1024-thread block requires.
//
// Mappings (verified round 4, downscaled): A-frag row = lane&15,
// k = kc*32 + (lane>>4)*8 + j. B = h broadcast into all 16 columns (value
// depends only on k) -> every C column equals y; C: col=lane&15,
// row=(lane>>4)*4+reg. Lane (g=lane>>4, j2=r16&3) finalizes column
// cm = w*16 + g*4 + j2 via a 2-level cndmask; copy r16<4 publishes.
// Per-row accumulation order is bit-identical to round 4.
// ONE barrier per step; h double-buffered f16 in LDS.
// ---------------------------------------------------------------------------
__global__ __launch_bounds__(1024, 1) void gru_kernel(
    const float* __restrict__ Whh, const float* __restrict__ bhh,
    const float* __restrict__ xw, float* __restrict__ zout)
{
  __shared__ __align__(16) _Float16 hbuf[2][HID];   // double-buffered h
  const int i    = threadIdx.x;
  const int w    = i >> 6;             // wave 0..15 -> columns w*16..w*16+15
  const int lane = i & 63;
  const int g    = lane >> 4;          // C-rows g*4..g*4+3; B k-sub g*8..+8
  const int r16  = lane & 15;          // A-fragment row within a 16-row tile
  const int j2   = r16 & 3;            // which acc reg this lane finalizes
  const int cm   = w * 16 + g * 4 + j2;
  const bool writer = r16 < 4;         // one finalizer copy publishes

  // --- resident A-fragments: [gate][kc], 96 regs ---
  half8_t A[3][8];
#pragma unroll
  for (int G = 0; G < 3; ++G) {
    const int row = G * 256 + w * 16 + r16;
    const float* wp = Whh + (size_t)row * 256 + g * 8;
#pragma unroll
    for (int kc = 0; kc < 8; ++kc) {
      const float4* w4 = (const float4*)(wp + kc * 32);
      float4 u = w4[0], v = w4[1];
      half8_t f;
      f[0] = (_Float16)u.x; f[1] = (_Float16)u.y;
      f[2] = (_Float16)u.z; f[3] = (_Float16)u.w;
      f[4] = (_Float16)v.x; f[5] = (_Float16)v.y;
      f[6] = (_Float16)v.z; f[7] = (_Float16)v.w;
      A[G][kc] = f;
    }
  }

  const float br  = bhh[cm];
  const float bz  = bhh[256 + cm];
  const float bnn = bhh[512 + cm];

  if (i < HID) hbuf[0][i] = (_Float16)0.0f;
  __syncthreads();

  float hreg = 0.0f;   // h[cm], tracked by all 4 finalizer copies
  float xr0 = xw[cm], xz0 = xw[256 + cm], xn0 = xw[512 + cm];

  const f32x4 zf = {0.f, 0.f, 0.f, 0.f};

  for (int s = 0; s < SEQ; ++s) {
    // issue next step's xW loads now (latency hidden behind the MFMAs)
    const size_t bnext = (size_t)(s + 1 < SEQ ? s + 1 : s) * G3;
    float xr1 = xw[bnext + cm], xz1 = xw[bnext + 256 + cm], xn1 = xw[bnext + 512 + cm];

    const _Float16* hc = hbuf[s & 1];

    // --- 24 MFMAs: 3 tiles x 8 k-chunks, depth-1 B-frag prefetch ---
    f32x4 acc[3];
    half8_t bq = *(const half8_t*)(hc + g * 8);            // kc = 0
    half8_t bp = *(const half8_t*)(hc + 32 + g * 8);       // kc = 1
#pragma unroll
    for (int t = 0; t < 3; ++t)
      acc[t] = __builtin_amdgcn_mfma_f32_16x16x32_f16(A[t][0], bq, zf, 0, 0, 0);
    bq = bp;
#pragma unroll
    for (int kc = 1; kc < 8; ++kc) {
      half8_t bn2;
      if (kc < 7) bn2 = *(const half8_t*)(hc + (kc + 1) * 32 + g * 8);
#pragma unroll
      for (int t = 0; t < 3; ++t)
        acc[t] = __builtin_amdgcn_mfma_f32_16x16x32_f16(A[t][kc], bq, acc[t], 0, 0, 0);
      if (kc < 7) bq = bn2;
    }

    // --- select this lane's y_r,y_z,y_n from the 4 replicated regs ---
#define SEL4(x, out) do {                          \
      float p0 = s0 ? (x)[1] : (x)[0];             \
      float p1 = s0 ? (x)[3] : (x)[2];             \
      out = s1 ? p1 : p0;                          \
    } while (0)
    const bool s0 = (j2 & 1) != 0, s1 = (j2 & 2) != 0;
    float yr, yz, yn;
    SEL4(acc[0], yr);
    SEL4(acc[1], yz);
    SEL4(acc[2], yn);
#undef SEL4

    // --- gate math for the one owned column (f32) ---
    float rg = sigmoidf_fast(yr + br + xr0);
    float zg = sigmoidf_fast(yz + bz + xz0);
    float ng = tanhf_fast(xn0 + rg * (yn + bnn));
    hreg = (1.0f - zg) * ng + zg * hreg;

    if (writer) {
      hbuf[(s + 1) & 1][cm] = (_Float16)hreg;
      zout[(size_t)s * HID + cm] = hreg;
    }
    __syncthreads();
    xr0 = xr1; xz0 = xz1; xn0 = xn1;
  }
}

// ---------------------------------------------------------------------------
// Phase C: NCE loss + accuracy. One block per t, 4 waves = 4 timespans.
// Reads f32 z straight from d_out.
// ---------------------------------------------------------------------------
__global__ __launch_bounds__(256) void cpc_kernel(
    const float* __restrict__ x, const float* __restrict__ zf,
    const float* __restrict__ rn, float* __restrict__ accum)
{
  __shared__ float zsh[HID];
  __shared__ float wsum[4];
  __shared__ float nce_s[4], acc_s[4];
  const int tt = TSTART + blockIdx.x;
  const int i = threadIdx.x;
  const int wave = i >> 6, lane = i & 63;

  float zi = zf[(size_t)tt * HID + i];
  zsh[i] = zi;
  float p = zi * zi;
#pragma unroll
  for (int off = 32; off; off >>= 1) p += __shfl_xor(p, off, 64);
  if (lane == 0) wsum[wave] = p;
  __syncthreads();
  float zn = fmaxf(sqrtf(wsum[0] + wsum[1] + wsum[2] + wsum[3]), 1e-8f);

  float z0 = zsh[lane], z1 = zsh[lane + 64], z2 = zsh[lane + 128], z3 = zsh[lane + 192];
  const int base = tt + wave + 1;   // pos index for timespan (wave+1)

  float tot[10];
#pragma unroll
  for (int n = 0; n < 10; ++n) {
    int idx = base + (n > 0 ? (NEGD + n - 1) : 0);
    const float* xr = x + (size_t)idx * HID;
    float q = xr[lane] * z0 + xr[lane + 64] * z1 + xr[lane + 128] * z2 + xr[lane + 192] * z3;
#pragma unroll
    for (int off = 32; off; off >>= 1) q += __shfl_xor(q, off, 64);
    tot[n] = q / (rn[idx] * zn);
  }
  float m = tot[0];
#pragma unroll
  for (int n = 1; n < 10; ++n) m = fmaxf(m, tot[n]);
  float se = 0.f;
#pragma unroll
  for (int n = 0; n < 10; ++n) se += expf(tot[n] - m);
  float logp0 = (tot[0] - m) - logf(se);
  float accv = (tot[0] >= m) ? 1.0f : 0.0f;  // argmax==0 iff tot[0] is the max

  if (lane == 0) { nce_s[wave] = -logp0; acc_s[wave] = accv; }
  __syncthreads();
  if (i == 0) {
    atomicAdd(accum,     nce_s[0] + nce_s[1] + nce_s[2] + nce_s[3]);
    atomicAdd(accum + 1, acc_s[0] + acc_s[1] + acc_s[2] + acc_s[3]);
  }
}

__global__ void fin_kernel(const float* __restrict__ accum,
                           float* __restrict__ out)
{
  if (threadIdx.x == 0) {
    out[(size_t)SEQ * HID]     = accum[0] / DENOMF;   // nce
    out[(size_t)SEQ * HID + 1] = accum[1] / DENOMF;   // acc
  }
}

// ---------------------------------------------------------------------------
extern "C" void kernel_launch(void* const* d_in, const int* in_sizes, int n_in,
                              void* d_out, int out_size, void* d_ws, size_t ws_size,
                              hipStream_t stream)
{
  // Inputs are f32 (reference dtypes). Output f32: z [SEQ*HID] | nce | acc.
  const float* data = (const float*)d_in[0];
  const float* Wih  = (const float*)d_in[1];
  const float* Whh  = (const float*)d_in[2];
  const float* bih  = (const float*)d_in[3];
  const float* bhh  = (const float*)d_in[4];
  float* out = (float*)d_out;

  // ws layout: xw f32 [SEQ*768] 25.17MB | rn f32 [SEQ] | accum f32 [2]
  char* p = (char*)d_ws;
  float* xw    = (float*)p;  p += (size_t)SEQ * G3 * sizeof(float);
  float* rn    = (float*)p;  p += (size_t)SEQ * sizeof(float);
  float* accum = (float*)p;

  init_kernel<<<1, 64, 0, stream>>>(accum);
  xw_kernel<<<dim3(256, 3), 256, 0, stream>>>(data, Wih, bih, xw);
  rnorm_kernel<<<SEQ / 4, 256, 0, stream>>>(data, rn);
  gru_kernel<<<1, 1024, 0, stream>>>(Whh, bhh, xw, out);
  cpc_kernel<<<TCNT, 256, 0, stream>>>(data, out, rn, accum);
  fin_kernel<<<1, 1, 0, stream>>>(accum, out);
}

// Round 10
// 7970.823 us; speedup vs baseline: 8.1058x; 1.4159x over previous
//
#include <hip/hip_runtime.h>

// Problem constants (from reference)
#define SEQ   8192
#define HID   256
#define G3    768      // 3*HID
#define TSTART 1024    // SEQ/8
#define NEGD  1365     // SEQ/6
#define TCNT  5791     // (SEQ - 10 - NEGD - 4 + 2) - TSTART
#define DENOMF 23164.0f // TCNT*4

typedef _Float16 half8_t __attribute__((ext_vector_type(8)));
typedef float    f32x4  __attribute__((ext_vector_type(4)));

__device__ __forceinline__ float sigmoidf_fast(float x) {
  return 1.0f / (1.0f + __expf(-x));
}
// tanh via sigmoid form: safe at both extremes (exp under/overflow -> +-1)
__device__ __forceinline__ float tanhf_fast(float x) {
  return 2.0f / (1.0f + __expf(-2.0f * x)) - 1.0f;
}

// ---------------------------------------------------------------------------
// init: zero the loss accumulators (ws is poisoned 0xAA every call)
// ---------------------------------------------------------------------------
__global__ void init_kernel(float* accum) {
  if (threadIdx.x < 2) accum[threadIdx.x] = 0.0f;
}

// ---------------------------------------------------------------------------
// Phase A: xW = data @ Wih^T + bih -> f32 [SEQ][768]. All f32.
// grid (256, 3), block 256. Thread owns output col o; 32-row x-tile in LDS.
// ---------------------------------------------------------------------------
__global__ __launch_bounds__(256) void xw_kernel(
    const float* __restrict__ data, const float* __restrict__ Wih,
    const float* __restrict__ bih, float* __restrict__ xw)
{
  __shared__ float4 xs4[32 * 64];   // 32 rows x 256 f32 = 32 KB
  const int o  = blockIdx.y * 256 + threadIdx.x;
  const int m0 = blockIdx.x * 32;

  float* xsf = (float*)xs4;
  for (int r = 0; r < 32; ++r)
    xsf[r * 256 + threadIdx.x] = data[(size_t)(m0 + r) * 256 + threadIdx.x];
  __syncthreads();

  const float b = bih[o];
  float acc[32];
#pragma unroll
  for (int r = 0; r < 32; ++r) acc[r] = b;

  const float4* wrow = (const float4*)(Wih + (size_t)o * 256);
  for (int kc = 0; kc < 4; ++kc) {
    float4 w[16];
#pragma unroll
    for (int j = 0; j < 16; ++j) w[j] = wrow[kc * 16 + j];
#pragma unroll
    for (int r = 0; r < 32; ++r) {
      const float4* xr = xs4 + r * 64 + kc * 16;
      float a0 = 0.f, a1 = 0.f, a2 = 0.f, a3 = 0.f;
#pragma unroll
      for (int j = 0; j < 4; ++j) {
        float4 x0 = xr[4 * j + 0], x1 = xr[4 * j + 1];
        float4 x2 = xr[4 * j + 2], x3 = xr[4 * j + 3];
        float4 w0 = w[4 * j + 0], w1 = w[4 * j + 1];
        float4 w2 = w[4 * j + 2], w3 = w[4 * j + 3];
        a0 = fmaf(w0.x, x0.x, fmaf(w0.y, x0.y, fmaf(w0.z, x0.z, fmaf(w0.w, x0.w, a0))));
        a1 = fmaf(w1.x, x1.x, fmaf(w1.y, x1.y, fmaf(w1.z, x1.z, fmaf(w1.w, x1.w, a1))));
        a2 = fmaf(w2.x, x2.x, fmaf(w2.y, x2.y, fmaf(w2.z, x2.z, fmaf(w2.w, x2.w, a2))));
        a3 = fmaf(w3.x, x3.x, fmaf(w3.y, x3.y, fmaf(w3.z, x3.z, fmaf(w3.w, x3.w, a3))));
      }
      acc[r] += (a0 + a1) + (a2 + a3);
    }
  }
  for (int r = 0; r < 32; ++r)
    xw[(size_t)(m0 + r) * G3 + o] = acc[r];
}

// ---------------------------------------------------------------------------
// data row norms: one wave per row (f32 data)
// ---------------------------------------------------------------------------
__global__ __launch_bounds__(256) void rnorm_kernel(
    const float* __restrict__ data, float* __restrict__ rn)
{
  int wave = threadIdx.x >> 6, lane = threadIdx.x & 63;
  int row = blockIdx.x * 4 + wave;
  const float* xr = data + (size_t)row * HID;
  float a = xr[lane], b = xr[lane + 64], c = xr[lane + 128], d = xr[lane + 192];
  float s = a * a + b * b + c * c + d * d;
#pragma unroll
  for (int off = 32; off; off >>= 1) s += __shfl_xor(s, off, 64);
  if (lane == 0) rn[row] = fmaxf(sqrtf(s), 1e-8f);
}

// ---------------------------------------------------------------------------
// Phase B: sequential GRU scan via MFMA matvec. ONE block, 512 threads
// (8 waves, 2/SIMD) -- the round-4-verified structure (7722us, passed),
// with tail-overlap trims. Round-9 lesson: per-step VALU overhead scales
// with THREAD count while MFMA work is fixed, so 512 threads is the sweet
// spot; the only recoverable cost is the exposed serial tail (~550 cyc of
// the 2262-cyc step; MFMA pipe floor ~1530).
//
// Trims vs round 4 (numerics bit-identical -- per-acc kc order unchanged):
//  * B-frags bf[0..7] loaded upfront (8 x ds_read_b128, compile-time
//    indexed), all 8 reads in flight at once.
//  * r,z tiles' 32 MFMAs issued first; their SEL + both sigmoids placed
//    BEFORE the 16 n-tile MFMAs -- VALU work overlaps the matrix pipe
//    (separate pipes, no data dependency).
//  * Unconditional next-step xW prefetch (last iter reads the rn region:
//    in-bounds, value discarded) + pointer-increment addressing.
//
// Mappings (verified round 4): A-frag row = lane&15, k = kc*32+(lane>>4)*8+j.
// B = h broadcast into all 16 columns -> every C column equals y.
// C: col=lane&15, row=(lane>>4)*4+reg. Lane (g, jsel=lane&7) finalizes
// column cm = w*32+(jsel>>2)*16+g*4+(jsel&3); copy r16<8 publishes.
// ONE barrier per step; h double-buffered f16 in LDS.
// ---------------------------------------------------------------------------
__global__ __launch_bounds__(512, 2) void gru_kernel(
    const float* __restrict__ Whh, const float* __restrict__ bhh,
    const float* __restrict__ xw, float* __restrict__ zout)
{
  __shared__ __align__(16) _Float16 hbuf[2][HID];   // double-buffered h
  const int i    = threadIdx.x;
  const int w    = i >> 6;
  const int lane = i & 63;
  const int g    = lane >> 4;          // C-rows g*4..g*4+3; B k-sub g*8..+8
  const int r16  = lane & 15;          // A-fragment row within a 16-row tile
  const int jsel = lane & 7;           // (t2,reg) this lane finalizes
  const int cm   = w * 32 + (jsel >> 2) * 16 + g * 4 + (jsel & 3);
  const bool writer = r16 < 8;         // one finalizer copy publishes

  // --- resident A-fragments: [G*2+t2][kc], 192 AGPR-backed regs ---
  half8_t A[6][8];
#pragma unroll
  for (int G = 0; G < 3; ++G)
#pragma unroll
    for (int t2 = 0; t2 < 2; ++t2) {
      const int row = G * 256 + w * 32 + t2 * 16 + r16;
      const float* wp = Whh + (size_t)row * 256 + g * 8;
#pragma unroll
      for (int kc = 0; kc < 8; ++kc) {
        const float4* w4 = (const float4*)(wp + kc * 32);
        float4 u = w4[0], v = w4[1];
        half8_t f;
        f[0] = (_Float16)u.x; f[1] = (_Float16)u.y;
        f[2] = (_Float16)u.z; f[3] = (_Float16)u.w;
        f[4] = (_Float16)v.x; f[5] = (_Float16)v.y;
        f[6] = (_Float16)v.z; f[7] = (_Float16)v.w;
        A[G * 2 + t2][kc] = f;
      }
    }

  const float br  = bhh[cm];
  const float bz  = bhh[256 + cm];
  const float bnn = bhh[512 + cm];

  if (i < HID) hbuf[0][i] = (_Float16)0.0f;
  __syncthreads();

  float hreg = 0.0f;   // h[cm], tracked by both r16-parity copies
  const float* xwp = xw;       // row-s pointer, += G3 per step
  float*       zp  = zout;     // row-s output pointer, += HID per step
  float xr0 = xwp[cm], xz0 = xwp[256 + cm], xn0 = xwp[512 + cm];

  const f32x4 zf = {0.f, 0.f, 0.f, 0.f};

  for (int s = 0; s < SEQ; ++s) {
    // next step's xW prefetch, unconditional (last iter reads into the rn
    // region: in-bounds garbage, never used)
    xwp += G3;
    float xr1 = xwp[cm], xz1 = xwp[256 + cm], xn1 = xwp[512 + cm];

    const _Float16* hc = hbuf[s & 1];

    // --- all 8 B-frags upfront (compile-time indexed; reads overlap) ---
    half8_t bf[8];
#pragma unroll
    for (int kc = 0; kc < 8; ++kc)
      bf[kc] = *(const half8_t*)(hc + kc * 32 + g * 8);

    // --- r,z tiles first: 32 MFMAs, 4 independent chains ---
    f32x4 acc[6];
#pragma unroll
    for (int t = 0; t < 4; ++t)
      acc[t] = __builtin_amdgcn_mfma_f32_16x16x32_f16(A[t][0], bf[0], zf, 0, 0, 0);
#pragma unroll
    for (int kc = 1; kc < 8; ++kc)
#pragma unroll
      for (int t = 0; t < 4; ++t)
        acc[t] = __builtin_amdgcn_mfma_f32_16x16x32_f16(A[t][kc], bf[kc], acc[t], 0, 0, 0);

    // --- r,z finalize on the VALU while n MFMAs (below) fill the pipe ---
#define SEL8(x, y, out) do {                       \
      float p0 = s0 ? (x)[1] : (x)[0];             \
      float p1 = s0 ? (x)[3] : (x)[2];             \
      float p2 = s0 ? (y)[1] : (y)[0];             \
      float p3 = s0 ? (y)[3] : (y)[2];             \
      float q0 = s1 ? p1 : p0;                     \
      float q1 = s1 ? p3 : p2;                     \
      out = s2 ? q1 : q0;                          \
    } while (0)
    const bool s0 = (jsel & 1) != 0, s1 = (jsel & 2) != 0, s2 = (jsel & 4) != 0;
    float yr, yz;
    SEL8(acc[0], acc[1], yr);
    SEL8(acc[2], acc[3], yz);
    float rg = sigmoidf_fast(yr + br + xr0);
    float zg = sigmoidf_fast(yz + bz + xz0);

    // --- n tiles: 16 MFMAs, 2 chains (other wave + the VALU ops above
    //     keep the pipes fed) ---
    acc[4] = __builtin_amdgcn_mfma_f32_16x16x32_f16(A[4][0], bf[0], zf, 0, 0, 0);
    acc[5] = __builtin_amdgcn_mfma_f32_16x16x32_f16(A[5][0], bf[0], zf, 0, 0, 0);
#pragma unroll
    for (int kc = 1; kc < 8; ++kc) {
      acc[4] = __builtin_amdgcn_mfma_f32_16x16x32_f16(A[4][kc], bf[kc], acc[4], 0, 0, 0);
      acc[5] = __builtin_amdgcn_mfma_f32_16x16x32_f16(A[5][kc], bf[kc], acc[5], 0, 0, 0);
    }

    float yn;
    SEL8(acc[4], acc[5], yn);
#undef SEL8

    float ng = tanhf_fast(xn0 + rg * (yn + bnn));
    hreg = (1.0f - zg) * ng + zg * hreg;

    if (writer) {
      hbuf[(s + 1) & 1][cm] = (_Float16)hreg;
      zp[cm] = hreg;
    }
    __syncthreads();
    zp += HID;
    xr0 = xr1; xz0 = xz1; xn0 = xn1;
  }
}

// ---------------------------------------------------------------------------
// Phase C: NCE loss + accuracy. One block per t, 4 waves = 4 timespans.
// Reads f32 z straight from d_out.
// ---------------------------------------------------------------------------
__global__ __launch_bounds__(256) void cpc_kernel(
    const float* __restrict__ x, const float* __restrict__ zf,
    const float* __restrict__ rn, float* __restrict__ accum)
{
  __shared__ float zsh[HID];
  __shared__ float wsum[4];
  __shared__ float nce_s[4], acc_s[4];
  const int tt = TSTART + blockIdx.x;
  const int i = threadIdx.x;
  const int wave = i >> 6, lane = i & 63;

  float zi = zf[(size_t)tt * HID + i];
  zsh[i] = zi;
  float p = zi * zi;
#pragma unroll
  for (int off = 32; off; off >>= 1) p += __shfl_xor(p, off, 64);
  if (lane == 0) wsum[wave] = p;
  __syncthreads();
  float zn = fmaxf(sqrtf(wsum[0] + wsum[1] + wsum[2] + wsum[3]), 1e-8f);

  float z0 = zsh[lane], z1 = zsh[lane + 64], z2 = zsh[lane + 128], z3 = zsh[lane + 192];
  const int base = tt + wave + 1;   // pos index for timespan (wave+1)

  float tot[10];
#pragma unroll
  for (int n = 0; n < 10; ++n) {
    int idx = base + (n > 0 ? (NEGD + n - 1) : 0);
    const float* xr = x + (size_t)idx * HID;
    float q = xr[lane] * z0 + xr[lane + 64] * z1 + xr[lane + 128] * z2 + xr[lane + 192] * z3;
#pragma unroll
    for (int off = 32; off; off >>= 1) q += __shfl_xor(q, off, 64);
    tot[n] = q / (rn[idx] * zn);
  }
  float m = tot[0];
#pragma unroll
  for (int n = 1; n < 10; ++n) m = fmaxf(m, tot[n]);
  float se = 0.f;
#pragma unroll
  for (int n = 0; n < 10; ++n) se += expf(tot[n] - m);
  float logp0 = (tot[0] - m) - logf(se);
  float accv = (tot[0] >= m) ? 1.0f : 0.0f;  // argmax==0 iff tot[0] is the max

  if (lane == 0) { nce_s[wave] = -logp0; acc_s[wave] = accv; }
  __syncthreads();
  if (i == 0) {
    atomicAdd(accum,     nce_s[0] + nce_s[1] + nce_s[2] + nce_s[3]);
    atomicAdd(accum + 1, acc_s[0] + acc_s[1] + acc_s[2] + acc_s[3]);
  }
}

__global__ void fin_kernel(const float* __restrict__ accum,
                           float* __restrict__ out)
{
  if (threadIdx.x == 0) {
    out[(size_t)SEQ * HID]     = accum[0] / DENOMF;   // nce
    out[(size_t)SEQ * HID + 1] = accum[1] / DENOMF;   // acc
  }
}

// ---------------------------------------------------------------------------
extern "C" void kernel_launch(void* const* d_in, const int* in_sizes, int n_in,
                              void* d_out, int out_size, void* d_ws, size_t ws_size,
                              hipStream_t stream)
{
  // Inputs are f32 (reference dtypes). Output f32: z [SEQ*HID] | nce | acc.
  const float* data = (const float*)d_in[0];
  const float* Wih  = (const float*)d_in[1];
  const float* Whh  = (const float*)d_in[2];
  const float* bih  = (const float*)d_in[3];
  const float* bhh  = (const float*)d_in[4];
  float* out = (float*)d_out;

  // ws layout: xw f32 [SEQ*768] 25.17MB | rn f32 [SEQ] | accum f32 [2]
  char* p = (char*)d_ws;
  float* xw    = (float*)p;  p += (size_t)SEQ * G3 * sizeof(float);
  float* rn    = (float*)p;  p += (size_t)SEQ * sizeof(float);
  float* accum = (float*)p;

  init_kernel<<<1, 64, 0, stream>>>(accum);
  xw_kernel<<<dim3(256, 3), 256, 0, stream>>>(data, Wih, bih, xw);
  rnorm_kernel<<<SEQ / 4, 256, 0, stream>>>(data, rn);
  gru_kernel<<<1, 512, 0, stream>>>(Whh, bhh, xw, out);
  cpc_kernel<<<TCNT, 256, 0, stream>>>(data, out, rn, accum);
  fin_kernel<<<1, 1, 0, stream>>>(accum, out);
}